// Round 1
// baseline (279.155 us; speedup 1.0000x reference)
//
#include <hip/hip_runtime.h>
#include <hip/hip_bf16.h>

#define DIN   4096
#define DOUT  11008
#define TM    64          // rows of x
#define KSPLIT 4
#define KCHUNK (DIN / KSPLIT)   // 1024

typedef __attribute__((ext_vector_type(8))) short  bf16x8;
typedef __attribute__((ext_vector_type(4))) float  f32x4;

// floor(log2(safe_amax)) - 2, clipped; returns scale and 1/scale (powers of 2)
__device__ inline void mx_block_scale(float amax, float& scale, float& inv_scale) {
    float safe = amax > 0.0f ? amax : 1.0f;
    int e = (int)((__float_as_uint(safe) >> 23) & 255) - 127;  // floor(log2) for normals; subnormals fold into the -127 clip
    int se = e - 2;
    if (se < -127) se = -127;          // E8M0_MIN clip (upper clip unreachable: se <= 125)
    scale     = ldexpf(1.0f, se);
    inv_scale = ldexpf(1.0f, -se);
}

// E2M1 quant-dequant of one element given the block scale
__device__ inline float mx_qd(float v, float scale, float inv_scale) {
    float a = fabsf(v) * inv_scale;    // exact: power-of-two mult
    a = fminf(a, 6.0f);                // FP4_MAX saturate
    float step, rstep;
    if (a < 2.0f)      { step = 0.5f; rstep = 2.0f; }
    else if (a < 4.0f) { step = 1.0f; rstep = 1.0f; }
    else               { step = 2.0f; rstep = 0.5f; }
    float q = rintf(a * rstep) * step; // rintf = round-half-even = jnp.round
    return copysignf(q * scale, v);
}

__device__ inline unsigned short f32_to_bf16_bits(float f) {
    // value always has <=2 mantissa bits -> truncation is exact
    return (unsigned short)(__float_as_uint(f) >> 16);
}

// ---------------- kernel 1: quantize x -> bf16 (exact) ----------------
// 64*4096 elems, 4 per thread, 8-thread groups = one 32-block
__global__ __launch_bounds__(256) void quant_x_kernel(const float* __restrict__ x,
                                                      unsigned short* __restrict__ x_dq) {
    int gid = blockIdx.x * 256 + threadIdx.x;       // 65536 threads
    const float4 v = *(const float4*)(x + (size_t)gid * 4);
    float am = fmaxf(fmaxf(fabsf(v.x), fabsf(v.y)), fmaxf(fabsf(v.z), fabsf(v.w)));
    am = fmaxf(am, __shfl_xor(am, 1));
    am = fmaxf(am, __shfl_xor(am, 2));
    am = fmaxf(am, __shfl_xor(am, 4));
    float scale, inv;
    mx_block_scale(am, scale, inv);
    ushort4 q;
    q.x = f32_to_bf16_bits(mx_qd(v.x, scale, inv));
    q.y = f32_to_bf16_bits(mx_qd(v.y, scale, inv));
    q.z = f32_to_bf16_bits(mx_qd(v.z, scale, inv));
    q.w = f32_to_bf16_bits(mx_qd(v.w, scale, inv));
    *(ushort4*)(x_dq + (size_t)gid * 4) = q;
}

// ---------------- kernel 2: quant-dequant bias, broadcast into out ----------------
// block = 64 threads (1 wave); 32-lane halves = one bias block each. grid = 172
__global__ __launch_bounds__(64) void init_out_kernel(const float* __restrict__ bias,
                                                      float* __restrict__ out) {
    int n = blockIdx.x * 64 + threadIdx.x;          // 172*64 = 11008 exact
    float v = bias[n];
    float am = fabsf(v);
    am = fmaxf(am, __shfl_xor(am, 1));
    am = fmaxf(am, __shfl_xor(am, 2));
    am = fmaxf(am, __shfl_xor(am, 4));
    am = fmaxf(am, __shfl_xor(am, 8));
    am = fmaxf(am, __shfl_xor(am, 16));
    float scale, inv;
    mx_block_scale(am, scale, inv);
    float b = mx_qd(v, scale, inv);
    for (int t = 0; t < TM; ++t)
        out[(size_t)t * DOUT + n] = b;
}

// ---------------- kernel 3: fused W quant + GEMM (bf16 MFMA), split-K atomics ----------------
// grid (344, KSPLIT), block 256 (4 waves). BN=32 cols, BK=32 per iter.
__global__ __launch_bounds__(256) void gemm_kernel(const unsigned short* __restrict__ x_dq,
                                                   const float* __restrict__ wgt,
                                                   float* __restrict__ out) {
    __shared__ unsigned short x_lds[TM * 32];   // 4 KB
    __shared__ unsigned short w_lds[32 * 32];   // 2 KB

    const int t     = threadIdx.x;
    const int lane  = t & 63;
    const int wid   = t >> 6;                   // wave 0..3 -> M rows [16w,16w+16)
    const int n0    = blockIdx.x * 32;
    const int kbase = blockIdx.y * KCHUNK;

    // staging roles
    const int wrow = t >> 3;                    // 0..31  (8 threads per W row)
    const int wcol = (t & 7) * 4;               // float4 within the 32-block
    const int xrow = t >> 2;                    // 0..63  (4 threads per x row)
    const int xcol = (t & 3) * 8;               // 8 bf16 = 16B

    const float*          wptr = wgt + (size_t)(n0 + wrow) * DIN + kbase + wcol;
    const unsigned short* xptr = x_dq + (size_t)xrow * DIN + kbase + xcol;

    // MFMA fragment LDS offsets (elements)
    const int a_off  = (wid * 16 + (lane & 15)) * 32 + (lane >> 4) * 8;
    const int b_off0 = (lane & 15) * 32 + (lane >> 4) * 8;
    const int b_off1 = b_off0 + 16 * 32;

    f32x4 acc0 = {0.f, 0.f, 0.f, 0.f};
    f32x4 acc1 = {0.f, 0.f, 0.f, 0.f};

    for (int kk = 0; kk < KCHUNK; kk += 32) {
        // --- load + quantize one 32x32 W tile ---
        const float4 wv = *(const float4*)(wptr + kk);
        float am = fmaxf(fmaxf(fabsf(wv.x), fabsf(wv.y)), fmaxf(fabsf(wv.z), fabsf(wv.w)));
        am = fmaxf(am, __shfl_xor(am, 1));
        am = fmaxf(am, __shfl_xor(am, 2));
        am = fmaxf(am, __shfl_xor(am, 4));      // absmax over the 8-lane group = 32-block
        float scale, inv;
        mx_block_scale(am, scale, inv);
        ushort4 qw;
        qw.x = f32_to_bf16_bits(mx_qd(wv.x, scale, inv));
        qw.y = f32_to_bf16_bits(mx_qd(wv.y, scale, inv));
        qw.z = f32_to_bf16_bits(mx_qd(wv.z, scale, inv));
        qw.w = f32_to_bf16_bits(mx_qd(wv.w, scale, inv));
        *(ushort4*)(w_lds + wrow * 32 + wcol) = qw;

        // --- stage 64x32 x_dq tile ---
        *(uint4*)(x_lds + xrow * 32 + xcol) = *(const uint4*)(xptr + kk);

        __syncthreads();

        bf16x8 af = *(const bf16x8*)(x_lds + a_off);
        bf16x8 b0 = *(const bf16x8*)(w_lds + b_off0);
        bf16x8 b1 = *(const bf16x8*)(w_lds + b_off1);
        acc0 = __builtin_amdgcn_mfma_f32_16x16x32_bf16(af, b0, acc0, 0, 0, 0);
        acc1 = __builtin_amdgcn_mfma_f32_16x16x32_bf16(af, b1, acc1, 0, 0, 0);

        __syncthreads();
    }

    // epilogue: C/D map col=lane&15, row=(lane>>4)*4+reg
    const int m = wid * 16 + ((lane >> 4) << 2);
    const int n = n0 + (lane & 15);
    for (int r = 0; r < 4; ++r) {
        atomicAdd(&out[(size_t)(m + r) * DOUT + n],      acc0[r]);
        atomicAdd(&out[(size_t)(m + r) * DOUT + n + 16], acc1[r]);
    }
}

extern "C" void kernel_launch(void* const* d_in, const int* in_sizes, int n_in,
                              void* d_out, int out_size, void* d_ws, size_t ws_size,
                              hipStream_t stream) {
    const float* x    = (const float*)d_in[0];   // [64, 4096]
    const float* wgt  = (const float*)d_in[1];   // [11008, 4096]
    const float* bias = (const float*)d_in[2];   // [11008]
    float* out = (float*)d_out;                  // [64, 11008]
    unsigned short* x_dq = (unsigned short*)d_ws;  // 512 KB bf16 scratch

    quant_x_kernel<<<256, 256, 0, stream>>>(x, x_dq);
    init_out_kernel<<<172, 64, 0, stream>>>(bias, out);
    gemm_kernel<<<dim3(DOUT / 32, KSPLIT), 256, 0, stream>>>(x_dq, wgt, out);
}